// Round 1
// baseline (535.591 us; speedup 1.0000x reference)
//
#include <hip/hip_runtime.h>

// 3x3 PCF soft-shadow, 2-pass tile binning.
// vis[i] = (1/9) * sum_{ii,jj} sigmoid((zbuf[b, clip(y+ii), clip(x+jj)] - (depth_z[i]-BIAS)) * 1000)
//
// P1: bin pixel coords into (chunk, y>>7) slabs as 4B records (idxLocal|x|ylow).
//     Per-thread LDS atomicAdd for slot allocation (no ballot/shfl chain).
// P2: per 4096-pixel chunk: stage depth window in LDS, sweep 16 y-tiles in
//     PAIRS (2 recs/thread in flight -> 6 gather loads outstanding), slab pair
//     ~2 MiB stays L2-resident per XCD even under drift, overwrite LDS slot
//     with vis, write window back fully coalesced.

#define SHARPNESS 1000.0f
#define BIAS 0.008f

#define S_IMG      2048
#define NBATCH     8
#define HWK        (1 << 20)
#define TILE_SHIFT 7
#define NTILES     16                       // 2048 >> 7, 1 MiB zbuf slab per batch
#define PPB        4096                     // pixels per chunk (16 KiB LDS window)
#define NBLOCKS    ((NBATCH * HWK) / PPB)   // 2048 = 8 blocks/CU, all resident
#define CPB        (HWK / PPB)              // 256 chunks per batch
#define SLAB_CAP   384                      // mean 256, sigma ~15.5 -> +8.3 sigma
#define REC_BYTES  ((size_t)NBLOCKS * NTILES * SLAB_CAP * 4ull)   // 50.3 MB
#define WS_NEED    (REC_BYTES + (size_t)NBLOCKS * NTILES * 4ull)

typedef float f4u __attribute__((ext_vector_type(4), aligned(4)));
typedef int   i4v __attribute__((ext_vector_type(4)));

__device__ __forceinline__ float sigf(float bb, float a) {
    return 1.0f / (1.0f + __expf((a - bb) * SHARPNESS));
}
__device__ __forceinline__ float selv(f4u v, int s) {
    return (s == 0) ? v.x : (s == 1) ? v.y : (s == 2) ? v.z : v.w;
}

// ---------------- Pass 1: bin 4B records into slabs ----------------
__global__ __launch_bounds__(256) void p1_bin(
    const int* __restrict__ xy_raw,
    unsigned* __restrict__ recs, unsigned* __restrict__ cnts)
{
    __shared__ unsigned cur[NTILES];
    const int blk = blockIdx.x;            // chunk id; batch = blk>>8
    const int tid = threadIdx.x;
    if (tid < NTILES) cur[tid] = 0;
    __syncthreads();

    const size_t pbase = (size_t)blk * PPB;
    const i4v* xy4 = (const i4v*)(xy_raw + 2 * pbase);   // 2 pixels per 16B
    unsigned* slab0 = recs + (size_t)blk * NTILES * SLAB_CAP;

#pragma unroll
    for (int j = 0; j < PPB / 512; ++j) {                // 8 iters, 2 px each
        const i4v q = __builtin_nontemporal_load(&xy4[j * 256 + tid]);
        const int il0 = (j * 256 + tid) * 2;
        const int t0  = q.y >> TILE_SHIFT;
        const int t1  = q.w >> TILE_SHIFT;
        const unsigned rec0 = (unsigned)il0
                            | ((unsigned)q.x << 12)
                            | ((unsigned)(q.y & ((1 << TILE_SHIFT) - 1)) << 23);
        const unsigned rec1 = (unsigned)(il0 + 1)
                            | ((unsigned)q.z << 12)
                            | ((unsigned)(q.w & ((1 << TILE_SHIFT) - 1)) << 23);
        const unsigned p0 = atomicAdd(&cur[t0], 1u);
        slab0[(size_t)t0 * SLAB_CAP + p0] = rec0;
        const unsigned p1 = atomicAdd(&cur[t1], 1u);
        slab0[(size_t)t1 * SLAB_CAP + p1] = rec1;
    }
    __syncthreads();
    if (tid < NTILES) cnts[blk * NTILES + tid] = cur[tid];
}

// ---------------- Pass 2: tile-pair-phased PCF, LDS pixel window ----------------
struct G9 { f4u v0, v1, v2; int x; };

__device__ __forceinline__ void g9_issue(G9& g, const float* __restrict__ zb,
                                         unsigned rec, int t) {
    const int x  = (int)((rec >> 12) & 0x7FFu);
    const int y  = (t << TILE_SHIFT) | (int)(rec >> 23);
    const int ym = (y > 0) ? y - 1 : 0;
    const int yp = (y < S_IMG - 1) ? y + 1 : S_IMG - 1;
    const int xb = min(max(x - 1, 0), S_IMG - 4);
    const float* base = zb + xb;
    g.v0 = *(const f4u*)(base + (size_t)ym * S_IMG);
    g.v1 = *(const f4u*)(base + (size_t)y  * S_IMG);
    g.v2 = *(const f4u*)(base + (size_t)yp * S_IMG);
    g.x  = x;
}

__device__ __forceinline__ float g9_eval(const G9& g, float a) {
    if (g.x >= 1 && g.x <= S_IMG - 3) {       // interior: selectors are 0,1,2
        return sigf(g.v0.x, a) + sigf(g.v0.y, a) + sigf(g.v0.z, a)
             + sigf(g.v1.x, a) + sigf(g.v1.y, a) + sigf(g.v1.z, a)
             + sigf(g.v2.x, a) + sigf(g.v2.y, a) + sigf(g.v2.z, a);
    } else {
        const int xb = min(max(g.x - 1, 0), S_IMG - 4);
        const int s0 = max(g.x - 1, 0) - xb;
        const int s1 = g.x - xb;
        const int s2 = min(g.x + 1, S_IMG - 1) - xb;
        return sigf(selv(g.v0, s0), a) + sigf(selv(g.v0, s1), a) + sigf(selv(g.v0, s2), a)
             + sigf(selv(g.v1, s0), a) + sigf(selv(g.v1, s1), a) + sigf(selv(g.v1, s2), a)
             + sigf(selv(g.v2, s0), a) + sigf(selv(g.v2, s1), a) + sigf(selv(g.v2, s2), a);
    }
}

__global__ __launch_bounds__(256, 8) void p2_pcf(
    const float* __restrict__ zbuf, const float* __restrict__ depth,
    const unsigned* __restrict__ recs, const unsigned* __restrict__ cnts,
    float* __restrict__ out)
{
    __shared__ float sd[PPB];              // 16 KiB: depth in, vis out
    const int g   = blockIdx.x;
    const int b   = g & (NBATCH - 1);      // batch; round-robin -> XCD-affine
    const int c   = g >> 3;                // chunk within batch
    const int tid = threadIdx.x;
    const int blk = b * CPB + c;           // P1 chunk id
    const size_t pbase = (size_t)blk * PPB;
    const float* zb = zbuf + (size_t)b * ((size_t)S_IMG * S_IMG);

    // stage depth window, coalesced
    const f4u* dw = (const f4u*)(depth + pbase);
#pragma unroll
    for (int j = 0; j < PPB / (256 * 4); ++j)
        ((f4u*)sd)[j * 256 + tid] = __builtin_nontemporal_load(&dw[j * 256 + tid]);
    __syncthreads();

    for (int t = 0; t < NTILES; t += 2) {  // all blocks sweep tile-pairs in phase
        const int s  = blk * NTILES + t;
        const int n0 = (int)cnts[s];
        const int n1 = (int)cnts[s + 1];
        const unsigned* sl0 = recs + (size_t)s * SLAB_CAP;
        const unsigned* sl1 = sl0 + SLAB_CAP;
        const int nm = (n0 > n1) ? n0 : n1;
        const int c0 = (n0 > 0) ? n0 - 1 : 0;   // clamp index; lanes past n do
        const int c1 = (n1 > 0) ? n1 - 1 : 0;   // dummy work, store is guarded
        for (int k = tid; k < nm; k += 256) {
            const unsigned r0 = __builtin_nontemporal_load(&sl0[min(k, c0)]);
            const unsigned r1 = __builtin_nontemporal_load(&sl1[min(k, c1)]);
            const int il0 = (int)(r0 & 0xFFFu);
            const int il1 = (int)(r1 & 0xFFFu);
            const float a0 = sd[il0] - BIAS;
            const float a1 = sd[il1] - BIAS;
            G9 g0, g1;
            g9_issue(g0, zb, r0, t);       // 6 gathers in flight before any eval
            g9_issue(g1, zb, r1, t + 1);
            const float vis0 = g9_eval(g0, a0);
            const float vis1 = g9_eval(g1, a1);
            if (k < n0) sd[il0] = vis0 * (1.0f / 9.0f);  // slot unique per record
            if (k < n1) sd[il1] = vis1 * (1.0f / 9.0f);
        }
    }
    __syncthreads();

    // write window back, coalesced NT
    f4u* ow = (f4u*)(out + pbase);
#pragma unroll
    for (int j = 0; j < PPB / (256 * 4); ++j)
        __builtin_nontemporal_store(((const f4u*)sd)[j * 256 + tid], &ow[j * 256 + tid]);
}

// ---------------- fallback: direct kernel ----------------
__global__ __launch_bounds__(256) void pcf_shadow_generic(
    const float* __restrict__ zbuf, const float* __restrict__ depth_z,
    const int2* __restrict__ xy, const int* __restrict__ image_size_p,
    float* __restrict__ out, int total, int zbuf_elems)
{
    const int i = blockIdx.x * blockDim.x + threadIdx.x;
    if (i >= total) return;
    const int S  = *image_size_p;
    const int SS = S * S;
    const int N  = zbuf_elems / SS;
    const int hwk = total / N;
    const int b   = i / hwk;
    const float a = depth_z[i] - BIAS;
    const int2 p  = xy[i];
    const float* base = zbuf + (size_t)b * (size_t)SS;
    float vis = 0.0f;
#pragma unroll
    for (int ii = -1; ii <= 1; ++ii) {
        const int yi = min(max(p.y + ii, 0), S - 1);
        const float* row = base + (size_t)yi * (size_t)S;
#pragma unroll
        for (int jj = -1; jj <= 1; ++jj) {
            const int xi = min(max(p.x + jj, 0), S - 1);
            vis += 1.0f / (1.0f + __expf((a - row[xi]) * SHARPNESS));
        }
    }
    out[i] = vis * (1.0f / 9.0f);
}

extern "C" void kernel_launch(void* const* d_in, const int* in_sizes, int n_in,
                              void* d_out, int out_size, void* d_ws, size_t ws_size,
                              hipStream_t stream) {
    const float* zbuf     = (const float*)d_in[0];
    const float* depth_z  = (const float*)d_in[1];
    const int*   xy_raw   = (const int*)d_in[2];
    const int*   img_size = (const int*)d_in[3];
    float*       out      = (float*)d_out;

    const int zbuf_elems = in_sizes[0];   // N*S*S
    const int total      = in_sizes[1];   // N*H*W*K

    if (zbuf_elems == NBATCH * S_IMG * S_IMG && total == NBATCH * HWK &&
        ws_size >= WS_NEED) {
        unsigned* recs = (unsigned*)d_ws;
        unsigned* cnts = (unsigned*)((char*)d_ws + REC_BYTES);
        p1_bin<<<NBLOCKS, 256, 0, stream>>>(xy_raw, recs, cnts);
        p2_pcf<<<NBLOCKS, 256, 0, stream>>>(zbuf, depth_z, recs, cnts, out);
    } else {
        const int block = 256;
        const int grid  = (total + block - 1) / block;
        pcf_shadow_generic<<<grid, block, 0, stream>>>(zbuf, depth_z, (const int2*)xy_raw,
                                                       img_size, out, total, zbuf_elems);
    }
}

// Round 2
// 466.078 us; speedup vs baseline: 1.1491x; 1.1491x over previous
//
#include <hip/hip_runtime.h>

// 3x3 PCF soft-shadow — single fused kernel.
// vis[i] = (1/9) * sum_{ii,jj} sigmoid((zbuf[b, clip(y+ii), clip(x+jj)] - (depth_z[i]-BIAS)) * 1000)
//
// Per 4096-pixel chunk (one 512-thread block):
//   A: read xy (NT), build 4B records (il|x|ylow) in VGPRs, LDS histogram over
//      8 y-tiles; stage depth window into LDS (NT, coalesced).
//   B: prefix-sum (thread 0), scatter records into LDS sorted by tile.
//   C: sweep records in rank order == ascending tile order (implicit phases ->
//      zbuf slab locality in L2/L3). 2-deep software pipeline: issue 3 gathers
//      for rec i+1 before evaluating rec i (sched_barrier pins the order).
//      vis overwrites the depth slot; coalesced NT writeback.
// No global record workspace: the 50 MB recs round-trip of the 2-pass design
// was evicting zbuf (128 MiB) from the 256 MiB L3; without it zbuf stays
// L3-resident and gathers never reach HBM.

#define SHARPNESS 1000.0f
#define BIAS 0.008f

#define S_IMG   2048
#define NBATCH  8
#define HWK     (1 << 20)
#define TSHIFT  8
#define NTILES  8                      // 2048 >> 8, 2 MiB zbuf slab per batch
#define PPB     4096                   // pixels per chunk
#define NTHR    512
#define NBLOCKS ((NBATCH * HWK) / PPB) // 2048
#define CPB     (HWK / PPB)            // 256 chunks per batch

typedef float f4u __attribute__((ext_vector_type(4), aligned(4)));
typedef int   i4v __attribute__((ext_vector_type(4)));

__device__ __forceinline__ float sigf(float bb, float a) {
    return 1.0f / (1.0f + __expf((a - bb) * SHARPNESS));
}
__device__ __forceinline__ float selv(f4u v, int s) {
    return (s == 0) ? v.x : (s == 1) ? v.y : (s == 2) ? v.z : v.w;
}

struct G9 { f4u v0, v1, v2; int x; };

__device__ __forceinline__ void g9_issue(G9& g, const float* __restrict__ zb,
                                         unsigned rec, int t) {
    const int x  = (int)((rec >> 12) & 0x7FFu);
    const int y  = (t << TSHIFT) | (int)(rec >> 23);
    const int ym = (y > 0) ? y - 1 : 0;
    const int yp = (y < S_IMG - 1) ? y + 1 : S_IMG - 1;
    const int xb = min(max(x - 1, 0), S_IMG - 4);
    const float* base = zb + xb;
    g.v0 = *(const f4u*)(base + (size_t)ym * S_IMG);
    g.v1 = *(const f4u*)(base + (size_t)y  * S_IMG);
    g.v2 = *(const f4u*)(base + (size_t)yp * S_IMG);
    g.x  = x;
}

__device__ __forceinline__ float g9_eval(const G9& g, float a) {
    if (g.x >= 1 && g.x <= S_IMG - 3) {       // interior: selectors are 0,1,2
        return sigf(g.v0.x, a) + sigf(g.v0.y, a) + sigf(g.v0.z, a)
             + sigf(g.v1.x, a) + sigf(g.v1.y, a) + sigf(g.v1.z, a)
             + sigf(g.v2.x, a) + sigf(g.v2.y, a) + sigf(g.v2.z, a);
    } else {
        const int xb = min(max(g.x - 1, 0), S_IMG - 4);
        const int s0 = max(g.x - 1, 0) - xb;
        const int s1 = g.x - xb;
        const int s2 = min(g.x + 1, S_IMG - 1) - xb;
        return sigf(selv(g.v0, s0), a) + sigf(selv(g.v0, s1), a) + sigf(selv(g.v0, s2), a)
             + sigf(selv(g.v1, s0), a) + sigf(selv(g.v1, s1), a) + sigf(selv(g.v1, s2), a)
             + sigf(selv(g.v2, s0), a) + sigf(selv(g.v2, s1), a) + sigf(selv(g.v2, s2), a);
    }
}

__global__ __launch_bounds__(NTHR, 8) void pcf_fused(
    const float* __restrict__ zbuf, const float* __restrict__ depth,
    const int* __restrict__ xy_raw, float* __restrict__ out)
{
    __shared__ float    sd[PPB];          // 16 KiB: depth in, vis out
    __shared__ unsigned srec[PPB];        // 16 KiB: records sorted by tile
    __shared__ unsigned cnt[NTILES];
    __shared__ unsigned cur[NTILES];
    __shared__ unsigned seg[NTILES + 1];

    const int g   = blockIdx.x;
    const int b   = g & (NBATCH - 1);     // batch; round-robin -> XCD-affine
    const int c   = g >> 3;
    const int tid = threadIdx.x;
    const int blk = b * CPB + c;
    const size_t pbase = (size_t)blk * PPB;
    const float* zb = zbuf + (size_t)b * ((size_t)S_IMG * S_IMG);

    if (tid < NTILES) cnt[tid] = 0;
    __syncthreads();

    // ---- Stage A: records to VGPRs + histogram; depth window to LDS ----
    unsigned rloc[8];
    unsigned tpack = 0;                    // 8 tiles x 3 bits
    const i4v* xy4 = (const i4v*)(xy_raw + 2 * pbase);   // 2 px per 16B
#pragma unroll
    for (int j = 0; j < 4; ++j) {
        const i4v q = __builtin_nontemporal_load(&xy4[j * NTHR + tid]);
        const int il0 = (j * NTHR + tid) * 2;
        const int t0  = q.y >> TSHIFT;
        const int t1  = q.w >> TSHIFT;
        rloc[2 * j]     = (unsigned)il0
                        | ((unsigned)q.x << 12)
                        | ((unsigned)(q.y & ((1 << TSHIFT) - 1)) << 23);
        rloc[2 * j + 1] = (unsigned)(il0 + 1)
                        | ((unsigned)q.z << 12)
                        | ((unsigned)(q.w & ((1 << TSHIFT) - 1)) << 23);
        tpack |= ((unsigned)t0 << (6 * j)) | ((unsigned)t1 << (6 * j + 3));
        atomicAdd(&cnt[t0], 1u);
        atomicAdd(&cnt[t1], 1u);
    }
    const f4u* dw = (const f4u*)(depth + pbase);
#pragma unroll
    for (int j = 0; j < PPB / (NTHR * 4); ++j)
        ((f4u*)sd)[j * NTHR + tid] = __builtin_nontemporal_load(&dw[j * NTHR + tid]);
    __syncthreads();

    // ---- Stage B: prefix + scatter into tile-sorted LDS array ----
    if (tid == 0) {
        unsigned s = 0;
#pragma unroll
        for (int t = 0; t < NTILES; ++t) { seg[t] = s; cur[t] = s; s += cnt[t]; }
        seg[NTILES] = s;                   // == PPB
    }
    __syncthreads();
#pragma unroll
    for (int j = 0; j < 8; ++j) {
        const int t = (int)((tpack >> (3 * j)) & 7u);
        const unsigned pos = atomicAdd(&cur[t], 1u);
        srec[pos] = rloc[j];
    }
    __syncthreads();

    // segment boundaries -> registers (rank k's tile = #boundaries <= k)
    const int e1 = (int)seg[1], e2 = (int)seg[2], e3 = (int)seg[3],
              e4 = (int)seg[4], e5 = (int)seg[5], e6 = (int)seg[6],
              e7 = (int)seg[7];
#define TILE8(k) ((int)((k) >= e1) + (int)((k) >= e2) + (int)((k) >= e3) + \
                  (int)((k) >= e4) + (int)((k) >= e5) + (int)((k) >= e6) + \
                  (int)((k) >= e7))

    // ---- Stage C: rank-order sweep (ascending tiles), 2-deep pipeline ----
    {
        unsigned recA = srec[tid];
        int  ilA = (int)(recA & 0xFFFu);
        G9 gA; g9_issue(gA, zb, recA, TILE8(tid));
        float aA = sd[ilA] - BIAS;
#pragma unroll
        for (int i = 0; i < PPB / NTHR - 1; ++i) {
            const int kB = (i + 1) * NTHR + tid;
            const unsigned recB = srec[kB];
            const int  ilB = (int)(recB & 0xFFFu);
            G9 gB; g9_issue(gB, zb, recB, TILE8(kB));
            const float aB = sd[ilB] - BIAS;
            __builtin_amdgcn_sched_barrier(0);   // keep B's gathers above A's eval
            sd[ilA] = g9_eval(gA, aA) * (1.0f / 9.0f);  // slot unique per record
            gA = gB; aA = aB; ilA = ilB;
        }
        sd[ilA] = g9_eval(gA, aA) * (1.0f / 9.0f);
    }
    __syncthreads();

    // ---- coalesced NT writeback ----
    f4u* ow = (f4u*)(out + pbase);
#pragma unroll
    for (int j = 0; j < PPB / (NTHR * 4); ++j)
        __builtin_nontemporal_store(((const f4u*)sd)[j * NTHR + tid], &ow[j * NTHR + tid]);
#undef TILE8
}

// ---------------- fallback: direct kernel ----------------
__global__ __launch_bounds__(256) void pcf_shadow_generic(
    const float* __restrict__ zbuf, const float* __restrict__ depth_z,
    const int2* __restrict__ xy, const int* __restrict__ image_size_p,
    float* __restrict__ out, int total, int zbuf_elems)
{
    const int i = blockIdx.x * blockDim.x + threadIdx.x;
    if (i >= total) return;
    const int S  = *image_size_p;
    const int SS = S * S;
    const int N  = zbuf_elems / SS;
    const int hwk = total / N;
    const int b   = i / hwk;
    const float a = depth_z[i] - BIAS;
    const int2 p  = xy[i];
    const float* base = zbuf + (size_t)b * (size_t)SS;
    float vis = 0.0f;
#pragma unroll
    for (int ii = -1; ii <= 1; ++ii) {
        const int yi = min(max(p.y + ii, 0), S - 1);
        const float* row = base + (size_t)yi * (size_t)S;
#pragma unroll
        for (int jj = -1; jj <= 1; ++jj) {
            const int xi = min(max(p.x + jj, 0), S - 1);
            vis += 1.0f / (1.0f + __expf((a - row[xi]) * SHARPNESS));
        }
    }
    out[i] = vis * (1.0f / 9.0f);
}

extern "C" void kernel_launch(void* const* d_in, const int* in_sizes, int n_in,
                              void* d_out, int out_size, void* d_ws, size_t ws_size,
                              hipStream_t stream) {
    const float* zbuf     = (const float*)d_in[0];
    const float* depth_z  = (const float*)d_in[1];
    const int*   xy_raw   = (const int*)d_in[2];
    const int*   img_size = (const int*)d_in[3];
    float*       out      = (float*)d_out;

    const int zbuf_elems = in_sizes[0];   // N*S*S
    const int total      = in_sizes[1];   // N*H*W*K

    if (zbuf_elems == NBATCH * S_IMG * S_IMG && total == NBATCH * HWK) {
        pcf_fused<<<NBLOCKS, NTHR, 0, stream>>>(zbuf, depth_z, xy_raw, out);
    } else {
        const int block = 256;
        const int grid  = (total + block - 1) / block;
        pcf_shadow_generic<<<grid, block, 0, stream>>>(zbuf, depth_z, (const int2*)xy_raw,
                                                       img_size, out, total, zbuf_elems);
    }
}